// Round 1
// baseline (209.224 us; speedup 1.0000x reference)
//
#include <hip/hip_runtime.h>
#include <math.h>

#define N_VOX (96*96*96)        // 884736 voxels per volume
#define NVOL 8                  // 4 pred + 4 target volumes
#define NEL (4*N_VOX)           // 3538944 elements in pred/target
#define PLANE (96*96)           // 9216

// tile geometry for local CCL: full d-span x TW x TH
#define TW 8
#define TH 8
#define TILES_W 12
#define TILES_H 12
#define TILE_VOX (96*TW*TH)     // 6144
#define TILE_WORDS (TILE_VOX/32) // 192

#define NBPLANES 11             // interior tile boundaries per axis
#define BOUND_VOX (2*NBPLANES*PLANE)      // 202752 edges/volume = 792*256
#define FACES_PER_VOL (2*2*NBPLANES*PLANE) // 405504 ints (w+h, 2 sides each)
#define HT_SIZE 512             // per-block LDS dedup entries (4 KB)
#define MAX_PROBES 32

// ---------------------------------------------------------------------------
// find with path compression on GLOBAL labels (root slots only). Writes via
// atomicMin only -> labels stay monotonically decreasing.
__device__ __forceinline__ int find_root_compress(int* __restrict__ L, int x) {
    int r = x;
    int p = L[r];
    while (p != r) { r = p; p = L[r]; }
    if (r != x) atomicMin(&L[x], r);
    return r;
}

// atomicMin union-find merge; returns # destroyed self-loops (union events).
__device__ __forceinline__ int merge_count(int* __restrict__ L, int l1, int l2) {
    int ev = 0;
    while (l1 != l2) {
        if (l1 < l2) { int t = l1; l1 = l2; l2 = t; }   // l1 > l2
        int l3 = atomicMin(&L[l1], l2);
        if (l3 == l1) { ev++; l1 = l2; }
        else l1 = l3;
    }
    return ev;
}

// merge on LDS labels (links only run-start slots)
__device__ __forceinline__ void merge_local(int* lab, int l1, int l2) {
    while (l1 != l2 && l1 != lab[l1]) l1 = lab[l1];
    while (l1 != l2 && l2 != lab[l2]) l2 = lab[l2];
    while (l1 != l2) {
        if (l1 < l2) { int t = l1; l1 = l2; l2 = t; }
        int l3 = atomicMin(&lab[l1], l2);
        l1 = (l3 == l1) ? l2 : l3;
    }
}

// start index of the consecutive-fg d-run containing fg voxel i (d = i%96).
__device__ __forceinline__ int run_start(const unsigned* fm, int i, int d) {
    int rowb = (i - d) >> 5;
    int k = d >> 5, bit = d & 31;
    unsigned below = bit ? (~fm[rowb + k] & ((1u << bit) - 1)) : 0u;
    int z = -1;
    if (below) z = (k << 5) + 31 - __builtin_clz(below);
    else if (k > 0) {
        unsigned n1 = ~fm[rowb + k - 1];
        if (n1) z = ((k - 1) << 5) + 31 - __builtin_clz(n1);
        else if (k > 1) {
            unsigned n0 = ~fm[rowb];
            if (n0) z = 31 - __builtin_clz(n0);
        }
    }
    return (i - d) + z + 1;
}

// ---------------------------------------------------------------------------
// Phase 1: run-based per-tile CCL in LDS. Outputs ONLY:
//   (a) compact face arrays (resolved global-root labels, -1 = bg) for the
//       4 interior-adjacent tile faces, int4-coalesced;
//   (b) sparse root-slot init Lg[g] = g for each tile root;
//   (c) rootcnt[v] += #tile roots; acc += focal partial (pred volumes).
// The full per-voxel label volume is never materialized.
__global__ __launch_bounds__(256) void ccl_local(const float* __restrict__ pred,
                                                 const float* __restrict__ targ,
                                                 int* __restrict__ Lg,
                                                 int* __restrict__ faces,
                                                 int* __restrict__ rootcnt,
                                                 float* __restrict__ acc,
                                                 int vbase) {
    __shared__ int lab[TILE_VOX];            // 24 KB
    __shared__ unsigned fm[TILE_WORDS];      // 768 B fg bit array
    __shared__ float fws[4];
    __shared__ int   iws[4];

    int vloc = blockIdx.y;
    int v = vbase + vloc;
    int tile = blockIdx.x;                   // 0..143
    int tw = tile % TILES_W, th = tile / TILES_W;
    int w0 = tw * TW, h0 = th * TH;
    int tbase = h0 * PLANE + w0 * 96;        // global index of tile origin
    int* Lvg = Lg + (size_t)vloc * N_VOX;
    int* Fw  = faces + (size_t)vloc * FACES_PER_VOL;   // [b][side][h*96+d]
    int* Fh  = Fw + 2 * NBPLANES * PLANE;              // [b][side][w*96+d]

    // ---- load: fg bits via ballot; fast focal partial for pred volumes ----
    float fsum = 0.0f;
    for (int it = 0; it < TILE_VOX / 256; it++) {
        int i = it * 256 + threadIdx.x;
        int lh = i / 768;                    // i = lh*768 + lw*96 + d
        int j = tbase + i + lh * 8448;       // global voxel index
        bool f;
        if (v < 4) {
            float xv = pred[(size_t)v * N_VOX + j];
            float tv = targ[(size_t)v * N_VOX + j];
            f = xv > 0.0f;                   // sigmoid(x)>0.5 <=> x>0
            float m   = (tv == 1.0f) ? -xv : xv;
            float at  = (tv == 1.0f) ? 0.25f : 0.75f;
            float e   = __expf(-fabsf(m));
            float inv = 1.0f / (1.0f + e);
            float sig = inv * ((m >= 0.0f) ? 1.0f : e);    // sigmoid(m)
            float sp  = fmaxf(m, 0.0f) + __logf(1.0f + e); // softplus(m)
            fsum += at * sig * sig * sp;
        } else {
            f = targ[(size_t)(v - 4) * N_VOX + j] > 0.5f;
        }
        unsigned long long bal = __ballot(f);
        if ((threadIdx.x & 63) == 0) {
            fm[i >> 5]       = (unsigned)bal;
            fm[(i >> 5) + 1] = (unsigned)(bal >> 32);
        }
        lab[i] = i;
    }
    __syncthreads();

    // ---- merge: word-level overlap-segment starts, w then h direction ----
    for (int t = threadIdx.x; t < 336; t += 256) {
        bool wdir = t < 168;
        int tt = wdir ? t : t - 168;
        int lh, lw, k;
        if (wdir) { lh = tt / 21; int rem = tt % 21; lw = rem / 3; k = rem % 3; }
        else      { lh = tt / 24; int rem = tt % 24; lw = rem / 3; k = rem % 3; }
        int wb = (lh * 8 + lw) * 3 + k;
        int nb = wb + (wdir ? 3 : 24);
        unsigned ov = fm[wb] & fm[nb];
        if (!ov) continue;
        unsigned carry = (k > 0) ? ((fm[wb - 1] & fm[nb - 1]) >> 31) : 0u;
        unsigned starts = ov & ~((ov << 1) | carry);
        int base_i = wb << 5;
        int dir = wdir ? 96 : 768;
        while (starts) {
            int b = __builtin_ctz(starts);
            starts &= starts - 1;
            int i = base_i + b;
            int d = (k << 5) + b;
            merge_local(lab, run_start(fm, i, d), run_start(fm, i + dir, d));
        }
    }
    __syncthreads();

    // ---- flatten + globalize + sparse root init ----
    int rc = 0;
    for (int t = threadIdx.x; t < TILE_WORDS; t += 256) {
        unsigned m = fm[t];
        if (!m) continue;
        unsigned carry = (t % 3) ? (fm[t - 1] >> 31) : 0u;
        unsigned starts = m & ~((m << 1) | carry);
        int base_i = t << 5;
        while (starts) {
            int b = __builtin_ctz(starts); starts &= starts - 1;
            int i = base_i + b;
            int r = i;
            int p = lab[r];
            while (p >= 0 && p != r) { r = p; p = lab[r]; }
            int g;
            if (p < 0) g = p;                        // finalized downstream
            else {                                   // p == r: raw root
                int gr = tbase + r + (r / 768) * 8448;
                g = ~gr;
                if (r == i) { rc++; Lvg[gr] = gr; }  // sparse root-slot init
            }
            lab[i] = g;                              // own slot: single writer
        }
    }
    __syncthreads();

    // ---- resolve + store the 4 interior-adjacent faces (int4 groups) ----
    // face f: 0 = lw=0 (side B of w-boundary tw-1), 1 = lw=7 (side A of tw),
    //         2 = lh=0 (side B of h-boundary th-1), 3 = lh=7 (side A of th)
    for (int t = threadIdx.x; t < 768; t += 256) {
        int f  = t / 192;
        int g  = t % 192;
        int u  = g / 24;                     // row within face (lh or lw)
        int d4 = (g % 24) * 4;
        int i0; int* dst;
        if (f == 0) {
            if (tw == 0) continue;
            i0  = u * 768 + d4;
            dst = Fw + ((tw - 1) * 2 + 1) * PLANE + (h0 + u) * 96 + d4;
        } else if (f == 1) {
            if (tw == TILES_W - 1) continue;
            i0  = u * 768 + 7 * 96 + d4;
            dst = Fw + (tw * 2) * PLANE + (h0 + u) * 96 + d4;
        } else if (f == 2) {
            if (th == 0) continue;
            i0  = u * 96 + d4;
            dst = Fh + ((th - 1) * 2 + 1) * PLANE + (w0 + u) * 96 + d4;
        } else {
            if (th == TILES_H - 1) continue;
            i0  = 7 * 768 + u * 96 + d4;
            dst = Fh + (th * 2) * PLANE + (w0 + u) * 96 + d4;
        }
        unsigned mw = fm[i0 >> 5];           // bits d4..d4+3 in one word
        int vals[4];
        bool prevf = false;
        for (int q = 0; q < 4; q++) {
            bool fb = (mw >> ((d4 & 31) + q)) & 1;
            if (fb) vals[q] = prevf ? vals[q - 1]
                                    : ~lab[run_start(fm, i0 + q, d4 + q)];
            else vals[q] = -1;
            prevf = fb;
        }
        *(int4*)dst = make_int4(vals[0], vals[1], vals[2], vals[3]);
    }

    // ---- wave-shuffle reductions: focal partial + local root count ----
    for (int off = 32; off; off >>= 1) {
        fsum += __shfl_down(fsum, off, 64);
        rc   += __shfl_down(rc,   off, 64);
    }
    int wid = threadIdx.x >> 6;
    if ((threadIdx.x & 63) == 0) { fws[wid] = fsum; iws[wid] = rc; }
    __syncthreads();
    if (threadIdx.x == 0) {
        float ft = fws[0] + fws[1] + fws[2] + fws[3];
        int   rt = iws[0] + iws[1] + iws[2] + iws[3];
        if (v < 4 && ft != 0.0f) atomicAdd(acc, ft);
        if (rt) atomicAdd(&rootcnt[v], rt);
    }
}

// ---------------------------------------------------------------------------
// Phase 2: one thread per boundary edge, reading ONLY the compact face
// arrays (coalesced) + the hot root slots. Edge processed only at overlap-
// segment starts along d; resolve roots first; LDS-dedup resolved pairs;
// merge with union-event counting.
__global__ __launch_bounds__(256) void ccl_boundary(int* __restrict__ Lg,
                                                    const int* __restrict__ faces,
                                                    int* __restrict__ events,
                                                    int vbase) {
    __shared__ unsigned long long ht[HT_SIZE];
    __shared__ int evacc;
    for (int i = threadIdx.x; i < HT_SIZE; i += 256) ht[i] = ~0ull;
    if (threadIdx.x == 0) evacc = 0;
    __syncthreads();

    int tid  = blockIdx.x * 256 + threadIdx.x;   // < BOUND_VOX
    int vloc = blockIdx.y;
    int* Lv = Lg + (size_t)vloc * N_VOX;
    const int* F = faces + (size_t)vloc * FACES_PER_VOL;

    int face = tid / PLANE;                      // 0..21
    int e    = tid % PLANE;
    const int* A;
    const int* B;
    if (face < NBPLANES) {
        A = F + (face * 2) * PLANE;
        B = F + (face * 2 + 1) * PLANE;
    } else {
        const int* Fh = F + 2 * NBPLANES * PLANE;
        int b = face - NBPLANES;
        A = Fh + (b * 2) * PLANE;
        B = Fh + (b * 2 + 1) * PLANE;
    }

    int a = A[e], b2 = B[e];
    int ev = 0;
    if (a >= 0 && b2 >= 0) {
        int d = e % 96;
        bool start = (d == 0) || (A[e - 1] < 0) || (B[e - 1] < 0);
        if (start) {
            a  = find_root_compress(Lv, a);
            b2 = find_root_compress(Lv, b2);
            if (a != b2) {
                int rmin = a < b2 ? a : b2;
                int rmax = a < b2 ? b2 : a;
                unsigned long long key = ((unsigned long long)rmin << 20) | (unsigned)rmax;
                unsigned long long hsh = (key ^ (key >> 29)) * 0x9E3779B97F4A7C15ull;
                unsigned slot = (unsigned)(hsh >> 43) & (HT_SIZE - 1);
                bool do_merge = false;
                for (int pr = 0; pr < MAX_PROBES; pr++) {
                    unsigned long long prev = atomicCAS(&ht[slot], ~0ull, key);
                    if (prev == ~0ull) { do_merge = true; break; }
                    if (prev == key)   { break; }
                    slot = (slot + 1) & (HT_SIZE - 1);
                    if (pr == MAX_PROBES - 1) do_merge = true;
                }
                if (do_merge) ev = merge_count(Lv, rmin, rmax);
            }
        }
    }
    if (ev) atomicAdd(&evacc, ev);
    __syncthreads();
    if (threadIdx.x == 0 && evacc) atomicAdd(&events[vbase + vloc], evacc);
}

// ---------------------------------------------------------------------------
// components[v] = rootcnt[v] - events[v]
__global__ void finalize_kernel(const float* __restrict__ acc,
                                const int* __restrict__ rootcnt,
                                const int* __restrict__ events,
                                float* __restrict__ out) {
    float focal = acc[0] / (float)NEL;
    float c[NVOL];
    for (int v = 0; v < NVOL; v++) c[v] = (float)(rootcnt[v] - events[v]);
    float dp0 = 0.5f * (c[0] + c[2]);
    float dp1 = 0.5f * (c[1] + c[3]);
    float dt0 = 0.5f * (c[4] + c[6]);
    float dt1 = 0.5f * (c[5] + c[7]);
    float topo = 0.5f * (fabsf(dp0 - dt0) + fabsf(dp1 - dt1));
    out[0] = focal + 0.1f * topo;
}

// ---------------------------------------------------------------------------
extern "C" void kernel_launch(void* const* d_in, const int* in_sizes, int n_in,
                              void* d_out, int out_size, void* d_ws, size_t ws_size,
                              hipStream_t stream) {
    const float* pred = (const float*)d_in[0];
    const float* targ = (const float*)d_in[1];
    float* out = (float*)d_out;

    // ws: [0] float acc; [64..] int rootcnt[8]; [128..] int events[8];
    // [256..) labels[vp*N_VOX] then faces[vp*FACES_PER_VOL]
    float* acc     = (float*)d_ws;
    int*   rootcnt = (int*)((char*)d_ws + 64);
    int*   events  = (int*)((char*)d_ws + 128);
    int*   labels  = (int*)((char*)d_ws + 256);

    size_t avail_ints = (ws_size > 256) ? (ws_size - 256) / 4 : 0;
    int vols_per_pass = (int)(avail_ints / (N_VOX + FACES_PER_VOL));
    if (vols_per_pass > NVOL) vols_per_pass = NVOL;
    if (vols_per_pass < 1) vols_per_pass = 1;
    int* faces = labels + (size_t)vols_per_pass * N_VOX;

    hipMemsetAsync(d_ws, 0, 256, stream);

    for (int vbase = 0; vbase < NVOL; vbase += vols_per_pass) {
        int nv = NVOL - vbase;
        if (nv > vols_per_pass) nv = vols_per_pass;
        dim3 tgrid(TILES_W * TILES_H, nv);
        ccl_local<<<tgrid, dim3(256), 0, stream>>>(pred, targ, labels, faces,
                                                   rootcnt, acc, vbase);
        dim3 bgrid(BOUND_VOX / 256, nv);
        ccl_boundary<<<bgrid, dim3(256), 0, stream>>>(labels, faces, events, vbase);
    }

    finalize_kernel<<<1, 1, 0, stream>>>(acc, rootcnt, events, out);
}